// Round 14
// baseline (816.717 us; speedup 1.0000x reference)
//
#include <hip/hip_runtime.h>
#include <cstdint>

typedef unsigned short u16;
typedef unsigned int u32;
typedef __attribute__((ext_vector_type(4))) int int4v;
typedef __attribute__((ext_vector_type(8))) short short8;
typedef __attribute__((ext_vector_type(8))) unsigned short u16x8;
typedef __attribute__((ext_vector_type(4))) float f32x4;

// d_out layout (floats): [xloss(1), nonpadded(1), pred(130048), Q(1), idx(1024)]
#define XLOSS_OFF 0
#define NPAD_OFF  1
#define PRED_OFF  2
#define Q_OFF     130050
#define IDX_OFF   130051

__device__ __forceinline__ u16 f2b(float f){
  union { float f; unsigned int i; } c; c.f = f;
  unsigned int i = c.i;
  unsigned int r = (i + 0x7FFFu + ((i >> 16) & 1u)) >> 16;
  return (u16)r;
}

#define LOG2E 1.442695040889634f
__device__ __forceinline__ float fast_sigmoid(float x){
  return __builtin_amdgcn_rcpf(1.f + __builtin_amdgcn_exp2f(-LOG2E*x));
}
__device__ __forceinline__ float fast_tanh(float x){
  return 1.f - 2.f*__builtin_amdgcn_rcpf(1.f + __builtin_amdgcn_exp2f((2.f*LOG2E)*x));
}

// ---------------- prep: Wout bf16 copy + zero scalar outputs ----------------
__global__ __launch_bounds__(256) void k_prep_wo(
    const float* __restrict__ Wo, u16* __restrict__ oWo, float* __restrict__ dout){
  int idx = blockIdx.x*256 + threadIdx.x;      // 16384 threads
  if (idx == 0){ dout[XLOSS_OFF]=0.f; dout[NPAD_OFF]=0.f; dout[Q_OFF]=0.f; }
  int row = idx >> 8, k = idx & 255;
  oWo[idx] = (row < 51) ? f2b(Wo[row*256 + k]) : (u16)0;
}

// ---------------- prep: per-row i8 quantization of Whh_{f,b,d} ----------------
__global__ __launch_bounds__(64) void k_prep_q(
    const float* __restrict__ Wf, const float* __restrict__ Wb, const float* __restrict__ Wd,
    signed char* __restrict__ qf, signed char* __restrict__ qb, signed char* __restrict__ qd,
    float* __restrict__ invf, float* __restrict__ invb, float* __restrict__ invd){
  const int row = blockIdx.x;                  // 0..2303
  const int mat = row / 768, r = row - mat*768;
  const float* W = (mat==0 ? Wf : (mat==1 ? Wb : Wd)) + (size_t)r*256;
  signed char* q = (mat==0 ? qf : (mat==1 ? qb : qd)) + (size_t)r*256;
  float* inv     = (mat==0 ? invf : (mat==1 ? invb : invd));
  const int lane = threadIdx.x;
  float4 v = *(const float4*)(W + lane*4);
  float m = fmaxf(fmaxf(fabsf(v.x),fabsf(v.y)), fmaxf(fabsf(v.z),fabsf(v.w)));
  #pragma unroll
  for (int off=32; off>0; off>>=1) m = fmaxf(m, __shfl_xor(m, off));
  m = fmaxf(m, 1e-20f);
  const float s = 127.f / m;
  int a0 = __float2int_rn(v.x*s), a1 = __float2int_rn(v.y*s);
  int a2 = __float2int_rn(v.z*s), a3 = __float2int_rn(v.w*s);
  u32 packed = (a0&255) | ((a1&255)<<8) | ((a2&255)<<16) | ((a3&255)<<24);
  *(u32*)(q + lane*4) = packed;
  if (lane == 0) inv[r] = m * (1.f/127.f);
}

// ---------------- prep: gi lookup tables G[v][768] (f32) ----------------
__global__ __launch_bounds__(256) void k_prep_g(
    const float* __restrict__ emb_e, const float* __restrict__ emb_d,
    const float* __restrict__ Wih_f, const float* __restrict__ bih_f, const float* __restrict__ bhh_f,
    const float* __restrict__ Wih_b, const float* __restrict__ bih_b, const float* __restrict__ bhh_b,
    const float* __restrict__ Wih_d,
    float* __restrict__ Gf, float* __restrict__ Gb, float* __restrict__ Gd){
  int idx = blockIdx.x*256 + threadIdx.x;   // exactly 3*51*768 threads
  int tab = idx / 39168;
  int rem = idx - tab*39168;
  int v = rem / 768;
  int n = rem - v*768;
  float acc = 0.f;
  if (tab == 0){
    const float* e = emb_e + v*64; const float* w = Wih_f + n*64;
    for (int k=0;k<64;k++) acc += e[k]*w[k];
    acc += bih_f[n] + (n < 512 ? bhh_f[n] : 0.f);
    Gf[rem] = acc;
  } else if (tab == 1){
    const float* e = emb_e + v*64; const float* w = Wih_b + n*64;
    for (int k=0;k<64;k++) acc += e[k]*w[k];
    acc += bih_b[n] + (n < 512 ? bhh_b[n] : 0.f);
    Gb[rem] = acc;
  } else {
    const float* e = emb_d + v*64; const float* w = Wih_d + n*96 + 32;
    for (int k=0;k<64;k++) acc += e[k]*w[k];
    Gd[rem] = acc;
  }
}

// ---------------- GRU scan: 8 rows/block, 256 thr, full weight residency ----------
// 256 threads = 4 waves, 8 batch rows/block. amdgpu_waves_per_eu(1,1): 1 wave/EU
// max -> per-wave register budget up to 512, so the 192 weight VGPRs (wave owns
// 64 h-cols x 3 gates = 12 n-tiles x 4 kt of mfma_i32_16x16x64_i8) are truly
// register-resident with ZERO spills. Encoder grid = 256 blocks -> all 256 CUs.
// G gate-inputs prefetched before the MFMA phase (L2 latency hidden under 48
// independent MFMAs); decoder zc prefetched ONCE (step-invariant). MFMA uses
// M=16 with rows 8..15 zero-padded (acc rows ignored). Gate math on lanes
// lhi<2. i8 h double-buffered in LDS, XOR swizzle byte = m*256 + (c^((m&15)<<4)).
template<int MODE>
__global__ __launch_bounds__(256)
__attribute__((amdgpu_waves_per_eu(1, 1)))
void k_gru(
    const signed char* __restrict__ W0, const signed char* __restrict__ W1,
    const float* __restrict__ I0, const float* __restrict__ I1,
    const float* __restrict__ G0, const float* __restrict__ G1,
    const float* __restrict__ bhh0, const float* __restrict__ bhh1,
    const int* __restrict__ x,
    const float* __restrict__ zc, const float* __restrict__ h0g,
    float* __restrict__ out_h, u16* __restrict__ ys){
  __shared__ signed char hbf[2*4096];               // [2][16 rows][256], swizzled; rows 8-15 stay 0
  __shared__ int xsh[1024];                         // [8][128] tokens
  __shared__ u16 ysh[(MODE==1) ? 2048 : 4];         // [8][256] bf16 h (decoder)

  const int tid = threadIdx.x;
  const int lane = tid & 63;
  const int wave = tid >> 6;                 // 0..3
  const int l15 = lane & 15, lhi = lane >> 4;

  bool fwd = true; int gb;
  const signed char* W; const float* G; const float* bhh; const float* invS;
  if (MODE == 0){
    int bi = blockIdx.x;
    fwd = bi < 128; gb = fwd ? bi : bi - 128;
    W = fwd ? W0 : W1; G = fwd ? G0 : G1; bhh = fwd ? bhh0 : bhh1;
    invS = fwd ? I0 : I1;
  } else {
    gb = blockIdx.x; W = W0; G = G0; bhh = bhh0; invS = I0;
  }
  const int b0 = gb * 8;
  const int nT = (MODE == 0) ? 128 : 127;
  const float HS    = (MODE == 0) ? 127.f : 63.f;
  const float invHS = (MODE == 0) ? (1.f/127.f) : (1.f/63.f);

  // ---- persistent weights: [gate][ct][kt], 48 x int4v = 192 VGPRs, pinned ----
  int4v wq[3][4][4];
  #pragma unroll
  for (int g=0; g<3; g++){
    #pragma unroll
    for (int ct=0; ct<4; ct++){
      const signed char* p = W + (size_t)(g*256 + wave*64 + ct*16 + l15)*256 + lhi*16;
      #pragma unroll
      for (int kt=0; kt<4; kt++)
        wq[g][ct][kt] = *(const int4v*)(p + kt*64);
    }
  }
  #pragma unroll
  for (int g=0; g<3; g++)
    #pragma unroll
    for (int ct=0; ct<4; ct++)
      #pragma unroll
      for (int kt=0; kt<4; kt++){ asm volatile("" : "+v"(wq[g][ct][kt])); }

  // dequant scales (per owned col) + n-gate bias
  float is_[3][4], bn_[4];
  #pragma unroll
  for (int ct=0; ct<4; ct++){
    const int col = wave*64 + ct*16 + l15;
    is_[0][ct] = invS[col]       * invHS;
    is_[1][ct] = invS[256 + col] * invHS;
    is_[2][ct] = invS[512 + col] * invHS;
    bn_[ct]    = bhh[512 + col];
  }

  // decoder: step-invariant zc contributions, prefetched ONCE (48 regs)
  float zv[3][16];
  if (MODE == 1 && lhi < 2){
    #pragma unroll
    for (int ct=0; ct<4; ct++){
      const int col = wave*64 + ct*16 + l15;
      #pragma unroll
      for (int r=0; r<4; r++){
        const int m = 4*lhi + r;
        const float* zp = zc + (size_t)(b0+m)*768 + col;
        zv[0][ct*4+r] = zp[0];
        zv[1][ct*4+r] = zp[256];
        zv[2][ct*4+r] = zp[512];
      }
    }
  }

  // stage tokens; zero hbf (rows 8-15 remain zero forever)
  for (int i = tid; i < 1024; i += 256) xsh[i] = x[b0*128 + i];
  for (int i = tid*4; i < 8192; i += 1024) *(int*)&hbf[i] = 0;

  // init h state (f32 regs) + decoder h0 into buf0
  float hreg[16];
  #pragma unroll
  for (int i=0;i<16;i++) hreg[i] = 0.f;
  if (MODE == 1 && lhi < 2){
    #pragma unroll
    for (int ct=0; ct<4; ct++){
      const int col = wave*64 + ct*16 + l15;
      #pragma unroll
      for (int r=0; r<4; r++){
        const int m = 4*lhi + r;
        float hv = h0g[(size_t)(b0+m)*256 + col];
        hreg[ct*4+r] = hv;
        int hq = __float2int_rn(fminf(fmaxf(hv*HS, -127.f), 127.f));
        hbf[m*256 + (col ^ ((m&15)<<4))] = (signed char)hq;
      }
    }
  }
  __syncthreads();

  // A-fragment byte offsets (row l15, K-slice kt*64 + lhi*16, XOR-swizzled)
  int aoff[4];
  #pragma unroll
  for (int kt=0; kt<4; kt++)
    aoff[kt] = l15*256 + ((kt*64 + lhi*16) ^ (l15<<4));

  int cur = 0;
  for (int t=0; t<nT; ++t){
    const signed char* hb = hbf + (cur<<12);
    int4v af[4];
    #pragma unroll
    for (int kt=0; kt<4; kt++) af[kt] = *(const int4v*)(hb + aoff[kt]);

    // prefetch G gate inputs for this step (hidden under the MFMA phase)
    const int te = (MODE==0 && !fwd) ? (127 - t) : t;
    float gv[3][16];
    if (lhi < 2){
      #pragma unroll
      for (int ct=0; ct<4; ct++){
        const int col = wave*64 + ct*16 + l15;
        #pragma unroll
        for (int r=0; r<4; r++){
          const int m = 4*lhi + r;
          const int tok = xsh[(m<<7) + te];
          const float* Gp = G + (size_t)tok*768 + col;
          gv[0][ct*4+r] = Gp[0];
          gv[1][ct*4+r] = Gp[256];
          gv[2][ct*4+r] = Gp[512];
        }
      }
    }

    // MFMA phase: 48 independent MFMAs (12 accs x 4 kt)
    int4v acc[3][4];
    #pragma unroll
    for (int g=0; g<3; g++)
      #pragma unroll
      for (int ct=0; ct<4; ct++) acc[g][ct] = (int4v){0,0,0,0};
    #pragma unroll
    for (int kt=0; kt<4; kt++)
      #pragma unroll
      for (int g=0; g<3; g++)
        #pragma unroll
        for (int ct=0; ct<4; ct++)
          acc[g][ct] = __builtin_amdgcn_mfma_i32_16x16x64_i8(af[kt], wq[g][ct][kt], acc[g][ct], 0,0,0);

    // gate phase (lanes lhi<2 hold rows 0..7)
    signed char* nbuf = hbf + ((cur^1)<<12);
    if (lhi < 2){
      #pragma unroll
      for (int ct=0; ct<4; ct++){
        const int col = wave*64 + ct*16 + l15;
        #pragma unroll
        for (int r=0; r<4; r++){
          const int idx = ct*4 + r;
          const int m = 4*lhi + r;
          float gr = gv[0][idx], gz = gv[1][idx], gn = gv[2][idx];
          if (MODE == 1){ gr += zv[0][idx]; gz += zv[1][idx]; gn += zv[2][idx]; }
          float ghr = (float)acc[0][ct][r] * is_[0][ct];
          float ghz = (float)acc[1][ct][r] * is_[1][ct];
          float ghn = (float)acc[2][ct][r] * is_[2][ct];
          float rg = fast_sigmoid(ghr + gr);
          float zg = fast_sigmoid(ghz + gz);
          float nn = fast_tanh(gn + rg*(ghn + bn_[ct]));
          float hv = nn + zg*(hreg[idx] - nn);
          hreg[idx] = hv;
          int hq = __float2int_rn(fminf(fmaxf(hv*HS, -127.f), 127.f));
          nbuf[m*256 + (col ^ ((m&15)<<4))] = (signed char)hq;
          if (MODE == 1) ysh[m*256 + col] = f2b(hv);
        }
      }
    }
    __syncthreads();
    if (MODE == 1){
      const int row = tid >> 5;            // 0..7
      const int c8  = (tid & 31) * 8;
      u16x8 v = *(const u16x8*)&ysh[row*256 + c8];
      *(u16x8*)&ys[((size_t)(b0+row)*127 + t)*256 + c8] = v;
      __syncthreads();
    }
    cur ^= 1;
  }

  if (MODE == 0 && lhi < 2){
    #pragma unroll
    for (int ct=0; ct<4; ct++){
      const int col = wave*64 + ct*16 + l15;
      #pragma unroll
      for (int r=0; r<4; r++){
        const int m = 4*lhi + r;
        out_h[(size_t)(b0+m)*512 + (fwd ? 0 : 256) + col] = hreg[ct*4+r];
      }
    }
  }
}

// ---------------- VQ: z, argmin codebook, Q, idx, decoder h0, zc ----------------
__global__ __launch_bounds__(64) void k_vq(
    const float* __restrict__ outH, const float* __restrict__ Wdown, const float* __restrict__ bdown,
    const float* __restrict__ cb, const float* __restrict__ Wup, const float* __restrict__ bup,
    const float* __restrict__ Wihd, const float* __restrict__ bihd, const float* __restrict__ bhhd,
    float* __restrict__ hidden, float* __restrict__ zc, float* __restrict__ dout){
  const int b = blockIdx.x;
  const int lane = threadIdx.x;
  __shared__ float oh[512];
  __shared__ float zsh[32];
  __shared__ float qsh[32];
  {
    const float* src = outH + (size_t)b*512 + lane*8;
    *(float4*)&oh[lane*8]   = *(const float4*)src;
    *(float4*)&oh[lane*8+4] = *(const float4*)(src+4);
  }
  __syncthreads();
  if (lane < 32){
    float acc = bdown[lane];
    const float* wr = Wdown + lane*512;
    for (int k=0;k<512;k++) acc += wr[k]*oh[k];
    zsh[lane] = acc;
  }
  __syncthreads();
  float bd = 3.4e38f; int bi = 0;
  for (int c8=0;c8<8;c8++){
    const int c = lane*8 + c8;
    const float* cr = cb + c*32;
    float d = 0.f;
    #pragma unroll
    for (int k=0;k<32;k++){ float df = zsh[k]-cr[k]; d += df*df; }
    if (d < bd){ bd = d; bi = c; }
  }
  #pragma unroll
  for (int offm=32; offm>0; offm>>=1){
    float od = __shfl_xor(bd, offm);
    int   oi = __shfl_xor(bi, offm);
    if (od < bd || (od == bd && oi < bi)){ bd = od; bi = oi; }
  }
  if (lane == 0){
    atomicAdd(&dout[Q_OFF], bd * (0.2f/32.f));
    dout[IDX_OFF + b] = (float)bi;
  }
  if (lane < 32) qsh[lane] = cb[(size_t)bi*32 + lane];
  __syncthreads();
  #pragma unroll
  for (int i=0;i<4;i++){
    const int o = lane*4 + i;
    float acc = bup[o];
    const float* wr = Wup + o*32;
    #pragma unroll
    for (int k=0;k<32;k++) acc += wr[k]*qsh[k];
    hidden[(size_t)b*256 + o] = acc;
  }
  #pragma unroll
  for (int i=0;i<12;i++){
    const int o = lane*12 + i;
    float acc = bihd[o] + (o < 512 ? bhhd[o] : 0.f);
    const float* wr = Wihd + (size_t)o*96;
    #pragma unroll
    for (int k=0;k<32;k++) acc += wr[k]*qsh[k];
    zc[(size_t)b*768 + o] = acc;
  }
}

// ---------------- output: logits, log-softmax, nll, argmax ----------------
__global__ __launch_bounds__(256) void k_out(
    const u16* __restrict__ ys, const u16* __restrict__ Wo,
    const float* __restrict__ bout, const int* __restrict__ x,
    float* __restrict__ dout){
  const int tid = threadIdx.x;
  const int w = tid >> 6, lane = tid & 63;
  const int l15 = lane & 15, lhi = lane >> 4;
  __shared__ float lg[4][32][66];
  const int rows0 = blockIdx.x*128 + w*32;
  const f32x4 fz = {0.f,0.f,0.f,0.f};
  #pragma unroll
  for (int mt=0; mt<2; mt++){
    const int rb = rows0 + mt*16;
    f32x4 acc[4];
    #pragma unroll
    for (int nt=0;nt<4;nt++) acc[nt] = fz;
    #pragma unroll
    for (int kt=0; kt<8; kt++){
      short8 a = *(const short8*)&ys[(size_t)(rb + l15)*256 + kt*32 + lhi*8];
      #pragma unroll
      for (int nt=0; nt<4; nt++){
        short8 bb = *(const short8*)&Wo[(size_t)(nt*16 + l15)*256 + kt*32 + lhi*8];
        acc[nt] = __builtin_amdgcn_mfma_f32_16x16x32_bf16(a, bb, acc[nt], 0, 0, 0);
      }
    }
    #pragma unroll
    for (int nt=0;nt<4;nt++){
      const int col = nt*16 + l15;
      const float bo = (col < 51) ? bout[col] : 0.f;
      #pragma unroll
      for (int r=0;r<4;r++){
        float v = (col < 51) ? (acc[nt][r] + bo) : -1e30f;
        lg[w][mt*16 + lhi*4 + r][col] = v;
      }
    }
  }
  __syncthreads();
  float xl = 0.f, ct = 0.f;
  if (lane < 32){
    const int grow = rows0 + lane;
    const float* Lr = &lg[w][lane][0];
    float m = Lr[0]; int am = 0;
    for (int i=1;i<51;i++){ float v = Lr[i]; if (v > m){ m = v; am = i; } }
    float s = 0.f;
    for (int i=0;i<51;i++) s += __expf(Lr[i] - m);
    const int bb = grow / 127;
    const int tt = grow - bb*127;
    const int tgt = x[bb*128 + tt + 1];
    const float nll = (m + __logf(s)) - Lr[tgt];
    const float mk = (tgt != 0) ? 1.f : 0.f;
    dout[PRED_OFF + grow] = (float)am;
    xl = nll * mk; ct = mk;
  }
  #pragma unroll
  for (int off=32; off>0; off>>=1){
    xl += __shfl_xor(xl, off);
    ct += __shfl_xor(ct, off);
  }
  if (lane == 0){
    atomicAdd(&dout[XLOSS_OFF], xl);
    atomicAdd(&dout[NPAD_OFF], ct);
  }
}

extern "C" void kernel_launch(void* const* d_in, const int* in_sizes, int n_in,
                              void* d_out, int out_size, void* d_ws, size_t ws_size,
                              hipStream_t stream){
  (void)in_sizes; (void)n_in; (void)out_size; (void)ws_size;
  const int*   x      = (const int*)  d_in[0];
  const float* emb_e  = (const float*)d_in[1];
  const float* emb_d  = (const float*)d_in[2];
  const float* Wih_f  = (const float*)d_in[3];
  const float* Whh_f  = (const float*)d_in[4];
  const float* bih_f  = (const float*)d_in[5];
  const float* bhh_f  = (const float*)d_in[6];
  const float* Wih_b  = (const float*)d_in[7];
  const float* Whh_b  = (const float*)d_in[8];
  const float* bih_b  = (const float*)d_in[9];
  const float* bhh_b  = (const float*)d_in[10];
  const float* Wdown  = (const float*)d_in[11];
  const float* bdown  = (const float*)d_in[12];
  const float* cbook  = (const float*)d_in[13];
  const float* Wup    = (const float*)d_in[14];
  const float* bup    = (const float*)d_in[15];
  const float* Wih_d  = (const float*)d_in[16];
  const float* Whh_d  = (const float*)d_in[17];
  const float* bih_d  = (const float*)d_in[18];
  const float* bhh_d  = (const float*)d_in[19];
  const float* Wout   = (const float*)d_in[20];
  const float* bout   = (const float*)d_in[21];
  float* dout = (float*)d_out;

  char* ws = (char*)d_ws;
  size_t off = 0;
  auto nxt = [&](size_t bytes)->char*{
    char* r = ws + off;
    off += (bytes + 255) & ~(size_t)255;
    return r;
  };
  signed char* Wq_f = (signed char*)nxt((size_t)196608);
  signed char* Wq_b = (signed char*)nxt((size_t)196608);
  signed char* Wq_d = (signed char*)nxt((size_t)196608);
  float* invF = (float*)nxt((size_t)768*4);
  float* invB = (float*)nxt((size_t)768*4);
  float* invD = (float*)nxt((size_t)768*4);
  float* Gf    = (float*)nxt((size_t)39168*4);
  float* Gb    = (float*)nxt((size_t)39168*4);
  float* Gd    = (float*)nxt((size_t)39168*4);
  u16*   Wo_bf = (u16*) nxt((size_t)16384*2);
  float* outH  = (float*)nxt((size_t)524288*4);
  float* hid   = (float*)nxt((size_t)262144*4);
  float* zcw   = (float*)nxt((size_t)786432*4);
  u16*   ysb   = (u16*)  nxt((size_t)33292288*2);

  hipLaunchKernelGGL(k_prep_wo, dim3(64), dim3(256), 0, stream, Wout, Wo_bf, dout);
  hipLaunchKernelGGL(k_prep_q, dim3(2304), dim3(64), 0, stream,
                     Whh_f, Whh_b, Whh_d, Wq_f, Wq_b, Wq_d, invF, invB, invD);
  hipLaunchKernelGGL(k_prep_g, dim3(459), dim3(256), 0, stream,
                     emb_e, emb_d, Wih_f, bih_f, bhh_f, Wih_b, bih_b, bhh_b, Wih_d,
                     Gf, Gb, Gd);
  hipLaunchKernelGGL((k_gru<0>), dim3(256), dim3(256), 0, stream,
                     Wq_f, Wq_b, invF, invB, Gf, Gb, bhh_f, bhh_b, x,
                     (const float*)nullptr, (const float*)nullptr, outH, (u16*)nullptr);
  hipLaunchKernelGGL(k_vq, dim3(1024), dim3(64), 0, stream,
                     outH, Wdown, bdown, cbook, Wup, bup, Wih_d, bih_d, bhh_d,
                     hid, zcw, dout);
  hipLaunchKernelGGL((k_gru<1>), dim3(128), dim3(256), 0, stream,
                     Wq_d, (const signed char*)nullptr, invD, (const float*)nullptr,
                     Gd, (const float*)nullptr, bhh_d, (const float*)nullptr, x,
                     zcw, hid, (float*)nullptr, ysb);
  hipLaunchKernelGGL(k_out, dim3(1016), dim3(256), 0, stream,
                     ysb, Wo_bf, bout, x, dout);
}

// Round 15
// 601.291 us; speedup vs baseline: 1.3583x; 1.3583x over previous
//
#include <hip/hip_runtime.h>
#include <cstdint>

typedef unsigned short u16;
typedef unsigned int u32;
typedef __attribute__((ext_vector_type(4))) int int4v;
typedef __attribute__((ext_vector_type(8))) short short8;
typedef __attribute__((ext_vector_type(4))) float f32x4;

// d_out layout (floats): [xloss(1), nonpadded(1), pred(130048), Q(1), idx(1024)]
#define XLOSS_OFF 0
#define NPAD_OFF  1
#define PRED_OFF  2
#define Q_OFF     130050
#define IDX_OFF   130051

__device__ __forceinline__ u16 f2b(float f){
  union { float f; unsigned int i; } c; c.f = f;
  unsigned int i = c.i;
  unsigned int r = (i + 0x7FFFu + ((i >> 16) & 1u)) >> 16;
  return (u16)r;
}

#define LOG2E 1.442695040889634f
__device__ __forceinline__ float fast_sigmoid(float x){
  return __builtin_amdgcn_rcpf(1.f + __builtin_amdgcn_exp2f(-LOG2E*x));
}
__device__ __forceinline__ float fast_tanh(float x){
  return 1.f - 2.f*__builtin_amdgcn_rcpf(1.f + __builtin_amdgcn_exp2f((2.f*LOG2E)*x));
}

// ---------------- prep: Wout bf16 copy + zero scalar outputs ----------------
__global__ __launch_bounds__(256) void k_prep_wo(
    const float* __restrict__ Wo, u16* __restrict__ oWo, float* __restrict__ dout){
  int idx = blockIdx.x*256 + threadIdx.x;      // 16384 threads
  if (idx == 0){ dout[XLOSS_OFF]=0.f; dout[NPAD_OFF]=0.f; dout[Q_OFF]=0.f; }
  int row = idx >> 8, k = idx & 255;
  oWo[idx] = (row < 51) ? f2b(Wo[row*256 + k]) : (u16)0;
}

// ---------------- prep: per-row i8 quantization of Whh_{f,b,d} ----------------
__global__ __launch_bounds__(64) void k_prep_q(
    const float* __restrict__ Wf, const float* __restrict__ Wb, const float* __restrict__ Wd,
    signed char* __restrict__ qf, signed char* __restrict__ qb, signed char* __restrict__ qd,
    float* __restrict__ invf, float* __restrict__ invb, float* __restrict__ invd){
  const int row = blockIdx.x;                  // 0..2303
  const int mat = row / 768, r = row - mat*768;
  const float* W = (mat==0 ? Wf : (mat==1 ? Wb : Wd)) + (size_t)r*256;
  signed char* q = (mat==0 ? qf : (mat==1 ? qb : qd)) + (size_t)r*256;
  float* inv     = (mat==0 ? invf : (mat==1 ? invb : invd));
  const int lane = threadIdx.x;
  float4 v = *(const float4*)(W + lane*4);
  float m = fmaxf(fmaxf(fabsf(v.x),fabsf(v.y)), fmaxf(fabsf(v.z),fabsf(v.w)));
  #pragma unroll
  for (int off=32; off>0; off>>=1) m = fmaxf(m, __shfl_xor(m, off));
  m = fmaxf(m, 1e-20f);
  const float s = 127.f / m;
  int a0 = __float2int_rn(v.x*s), a1 = __float2int_rn(v.y*s);
  int a2 = __float2int_rn(v.z*s), a3 = __float2int_rn(v.w*s);
  u32 packed = (a0&255) | ((a1&255)<<8) | ((a2&255)<<16) | ((a3&255)<<24);
  *(u32*)(q + lane*4) = packed;
  if (lane == 0) inv[r] = m * (1.f/127.f);
}

// ---------------- prep: gi lookup tables G[v][768] (f32) ----------------
__global__ __launch_bounds__(256) void k_prep_g(
    const float* __restrict__ emb_e, const float* __restrict__ emb_d,
    const float* __restrict__ Wih_f, const float* __restrict__ bih_f, const float* __restrict__ bhh_f,
    const float* __restrict__ Wih_b, const float* __restrict__ bih_b, const float* __restrict__ bhh_b,
    const float* __restrict__ Wih_d,
    float* __restrict__ Gf, float* __restrict__ Gb, float* __restrict__ Gd){
  int idx = blockIdx.x*256 + threadIdx.x;   // exactly 3*51*768 threads
  int tab = idx / 39168;
  int rem = idx - tab*39168;
  int v = rem / 768;
  int n = rem - v*768;
  float acc = 0.f;
  if (tab == 0){
    const float* e = emb_e + v*64; const float* w = Wih_f + n*64;
    for (int k=0;k<64;k++) acc += e[k]*w[k];
    acc += bih_f[n] + (n < 512 ? bhh_f[n] : 0.f);
    Gf[rem] = acc;
  } else if (tab == 1){
    const float* e = emb_e + v*64; const float* w = Wih_b + n*64;
    for (int k=0;k<64;k++) acc += e[k]*w[k];
    acc += bih_b[n] + (n < 512 ? bhh_b[n] : 0.f);
    Gb[rem] = acc;
  } else {
    const float* e = emb_d + v*64; const float* w = Wih_d + n*96 + 32;
    for (int k=0;k<64;k++) acc += e[k]*w[k];
    Gd[rem] = acc;
  }
}

// ---------------- GRU scan: 512 thr, i8 weights resident, 2 waves/SIMD ----------
// 8 waves, 16 batch rows/block. Wave w owns h-cols {32w+l15, 32w+16+l15} for ALL
// 3 gates: 6 n-tiles x 4 kt of mfma_i32_16x16x64_i8 = 24 int4v = 96 weight VGPRs,
// pinned, under the measured 65536-reg/workgroup cap (512thr -> 128/lane): only
// ~15 working regs spill (vs ~100 in the bf16 twin R9). waves_per_eu(2,2) keeps
// 2 waves/SIMD for latency hiding of the gate-phase G gathers. All 16 MFMA rows
// valid. Gates fully in-register; h f32 in regs; i8 h double-buffered in LDS
// (16B-granule XOR swizzle, R11-verified). ONE barrier per step.
template<int MODE>
__global__ __launch_bounds__(512)
__attribute__((amdgpu_waves_per_eu(2, 2)))
void k_gru(
    const signed char* __restrict__ W0, const signed char* __restrict__ W1,
    const float* __restrict__ I0, const float* __restrict__ I1,
    const float* __restrict__ G0, const float* __restrict__ G1,
    const float* __restrict__ bhh0, const float* __restrict__ bhh1,
    const int* __restrict__ x,
    const float* __restrict__ zc, const float* __restrict__ h0g,
    float* __restrict__ out_h, u16* __restrict__ ys){
  __shared__ signed char hbf[2*4096];               // [2][16 rows][256], swizzled
  __shared__ int xsh[2048];                         // [16][128] tokens

  const int tid = threadIdx.x;
  const int lane = tid & 63;
  const int wave = tid >> 6;                 // 0..7
  const int l15 = lane & 15, lhi = lane >> 4;

  bool fwd = true; int gb;
  const signed char* W; const float* G; const float* bhh; const float* invS;
  if (MODE == 0){
    int bi = blockIdx.x;
    fwd = bi < 64; gb = fwd ? bi : bi - 64;
    W = fwd ? W0 : W1; G = fwd ? G0 : G1; bhh = fwd ? bhh0 : bhh1;
    invS = fwd ? I0 : I1;
  } else {
    gb = blockIdx.x; W = W0; G = G0; bhh = bhh0; invS = I0;
  }
  const int b0 = gb * 16;
  const int nT = (MODE == 0) ? 128 : 127;
  const float HS    = (MODE == 0) ? 127.f : 63.f;
  const float invHS = (MODE == 0) ? (1.f/127.f) : (1.f/63.f);

  const int ca  = wave*32 + l15;             // first owned col
  const int cb2 = ca + 16;                   // second owned col

  // ---- persistent weights: [gate*2+half][kt], 24 x int4v = 96 VGPRs, pinned ----
  int4v wq[6][4];
  #pragma unroll
  for (int g=0; g<3; g++){
    #pragma unroll
    for (int hh=0; hh<2; hh++){
      const signed char* p = W + (size_t)(g*256 + wave*32 + hh*16 + l15)*256 + lhi*16;
      #pragma unroll
      for (int kt=0; kt<4; kt++)
        wq[g*2+hh][kt] = *(const int4v*)(p + kt*64);
    }
  }
  #pragma unroll
  for (int kt=0; kt<4; kt++){
    asm volatile("" : "+v"(wq[0][kt]));
    asm volatile("" : "+v"(wq[1][kt]));
    asm volatile("" : "+v"(wq[2][kt]));
    asm volatile("" : "+v"(wq[3][kt]));
    asm volatile("" : "+v"(wq[4][kt]));
    asm volatile("" : "+v"(wq[5][kt]));
  }
  // dequant scales (weight-row scale x h scale) + n-gate biases
  const float is0 = invS[ca]        * invHS;   // r, col ca
  const float is1 = invS[cb2]       * invHS;   // r, col cb2
  const float is2 = invS[256 + ca]  * invHS;   // z
  const float is3 = invS[256 + cb2] * invHS;
  const float is4 = invS[512 + ca]  * invHS;   // n
  const float is5 = invS[512 + cb2] * invHS;
  const float bn0 = bhh[512 + ca];
  const float bn1 = bhh[512 + cb2];

  // stage tokens
  for (int i = tid; i < 2048; i += 512) xsh[i] = x[b0*128 + i];

  // init h (f32 regs) + hbf[0] (i8, full-XOR swizzle on each col)
  float hr0[4], hr1[4];
  #pragma unroll
  for (int r=0;r<4;r++){
    const int m = 4*lhi + r;
    const int sw = (m&15)<<4;
    float v0 = (MODE==0) ? 0.f : h0g[(size_t)(b0+m)*256 + ca];
    float v1 = (MODE==0) ? 0.f : h0g[(size_t)(b0+m)*256 + cb2];
    hr0[r] = v0; hr1[r] = v1;
    int q0 = __float2int_rn(fminf(fmaxf(v0*HS, -127.f), 127.f));
    int q1 = __float2int_rn(fminf(fmaxf(v1*HS, -127.f), 127.f));
    hbf[m*256 + (ca  ^ sw)] = (signed char)q0;
    hbf[m*256 + (cb2 ^ sw)] = (signed char)q1;
  }
  __syncthreads();

  // A-fragment byte offsets (row l15, K-slice kt*64 + lhi*16, XOR-swizzled)
  int aoff[4];
  #pragma unroll
  for (int kt=0; kt<4; kt++)
    aoff[kt] = l15*256 + ((kt*64 + lhi*16) ^ (l15<<4));

  int cur = 0;
  for (int t=0; t<nT; ++t){
    const signed char* hb = hbf + (cur<<12);
    int4v af[4];
    #pragma unroll
    for (int kt=0; kt<4; kt++) af[kt] = *(const int4v*)(hb + aoff[kt]);

    int4v acc[6];
    #pragma unroll
    for (int j=0;j<6;j++) acc[j] = (int4v){0,0,0,0};
    #pragma unroll
    for (int kt=0; kt<4; kt++)
      #pragma unroll
      for (int j=0;j<6;j++)
        acc[j] = __builtin_amdgcn_mfma_i32_16x16x64_i8(af[kt], wq[j][kt], acc[j], 0,0,0);

    const int te = (MODE==0 && !fwd) ? (127 - t) : t;
    signed char* nbuf = hbf + ((cur^1)<<12);
    #pragma unroll
    for (int r=0;r<4;r++){
      const int m = 4*lhi + r;
      const int tok = xsh[(m<<7) + te];
      const float* Gp = G + (size_t)tok*768;
      float gr0 = Gp[ca],  gz0 = Gp[256+ca],  gn0 = Gp[512+ca];
      float gr1 = Gp[cb2], gz1 = Gp[256+cb2], gn1 = Gp[512+cb2];
      if (MODE==1){
        const float* zp = zc + (size_t)(b0+m)*768;
        gr0 += zp[ca];  gz0 += zp[256+ca];  gn0 += zp[512+ca];
        gr1 += zp[cb2]; gz1 += zp[256+cb2]; gn1 += zp[512+cb2];
      }
      const int sw = (m&15)<<4;
      // half 0 (col ca)
      {
        float rg = fast_sigmoid((float)acc[0][r]*is0 + gr0);
        float zg = fast_sigmoid((float)acc[2][r]*is2 + gz0);
        float nn = fast_tanh(gn0 + rg*((float)acc[4][r]*is4 + bn0));
        float hv = nn + zg*(hr0[r] - nn);
        hr0[r] = hv;
        int hq = __float2int_rn(fminf(fmaxf(hv*HS, -127.f), 127.f));
        nbuf[m*256 + (ca ^ sw)] = (signed char)hq;
        if (MODE == 1) ys[((size_t)(b0+m)*127 + t)*256 + ca] = f2b(hv);
      }
      // half 1 (col cb2)
      {
        float rg = fast_sigmoid((float)acc[1][r]*is1 + gr1);
        float zg = fast_sigmoid((float)acc[3][r]*is3 + gz1);
        float nn = fast_tanh(gn1 + rg*((float)acc[5][r]*is5 + bn1));
        float hv = nn + zg*(hr1[r] - nn);
        hr1[r] = hv;
        int hq = __float2int_rn(fminf(fmaxf(hv*HS, -127.f), 127.f));
        nbuf[m*256 + (cb2 ^ sw)] = (signed char)hq;
        if (MODE == 1) ys[((size_t)(b0+m)*127 + t)*256 + cb2] = f2b(hv);
      }
    }
    __syncthreads();
    cur ^= 1;
  }

  if (MODE == 0){
    #pragma unroll
    for (int r=0;r<4;r++){
      const int m = 4*lhi + r;
      float* dst = out_h + (size_t)(b0+m)*512 + (fwd ? 0 : 256);
      dst[ca]  = hr0[r];
      dst[cb2] = hr1[r];
    }
  }
}

// ---------------- VQ: z, argmin codebook, Q, idx, decoder h0, zc ----------------
__global__ __launch_bounds__(64) void k_vq(
    const float* __restrict__ outH, const float* __restrict__ Wdown, const float* __restrict__ bdown,
    const float* __restrict__ cb, const float* __restrict__ Wup, const float* __restrict__ bup,
    const float* __restrict__ Wihd, const float* __restrict__ bihd, const float* __restrict__ bhhd,
    float* __restrict__ hidden, float* __restrict__ zc, float* __restrict__ dout){
  const int b = blockIdx.x;
  const int lane = threadIdx.x;
  __shared__ float oh[512];
  __shared__ float zsh[32];
  __shared__ float qsh[32];
  {
    const float* src = outH + (size_t)b*512 + lane*8;
    *(float4*)&oh[lane*8]   = *(const float4*)src;
    *(float4*)&oh[lane*8+4] = *(const float4*)(src+4);
  }
  __syncthreads();
  if (lane < 32){
    float acc = bdown[lane];
    const float* wr = Wdown + lane*512;
    for (int k=0;k<512;k++) acc += wr[k]*oh[k];
    zsh[lane] = acc;
  }
  __syncthreads();
  float bd = 3.4e38f; int bi = 0;
  for (int c8=0;c8<8;c8++){
    const int c = lane*8 + c8;
    const float* cr = cb + c*32;
    float d = 0.f;
    #pragma unroll
    for (int k=0;k<32;k++){ float df = zsh[k]-cr[k]; d += df*df; }
    if (d < bd){ bd = d; bi = c; }
  }
  #pragma unroll
  for (int offm=32; offm>0; offm>>=1){
    float od = __shfl_xor(bd, offm);
    int   oi = __shfl_xor(bi, offm);
    if (od < bd || (od == bd && oi < bi)){ bd = od; bi = oi; }
  }
  if (lane == 0){
    atomicAdd(&dout[Q_OFF], bd * (0.2f/32.f));
    dout[IDX_OFF + b] = (float)bi;
  }
  if (lane < 32) qsh[lane] = cb[(size_t)bi*32 + lane];
  __syncthreads();
  #pragma unroll
  for (int i=0;i<4;i++){
    const int o = lane*4 + i;
    float acc = bup[o];
    const float* wr = Wup + o*32;
    #pragma unroll
    for (int k=0;k<32;k++) acc += wr[k]*qsh[k];
    hidden[(size_t)b*256 + o] = acc;
  }
  #pragma unroll
  for (int i=0;i<12;i++){
    const int o = lane*12 + i;
    float acc = bihd[o] + (o < 512 ? bhhd[o] : 0.f);
    const float* wr = Wihd + (size_t)o*96;
    #pragma unroll
    for (int k=0;k<32;k++) acc += wr[k]*qsh[k];
    zc[(size_t)b*768 + o] = acc;
  }
}

// ---------------- output: logits, log-softmax, nll, argmax ----------------
__global__ __launch_bounds__(256) void k_out(
    const u16* __restrict__ ys, const u16* __restrict__ Wo,
    const float* __restrict__ bout, const int* __restrict__ x,
    float* __restrict__ dout){
  const int tid = threadIdx.x;
  const int w = tid >> 6, lane = tid & 63;
  const int l15 = lane & 15, lhi = lane >> 4;
  __shared__ float lg[4][32][66];
  const int rows0 = blockIdx.x*128 + w*32;
  const f32x4 fz = {0.f,0.f,0.f,0.f};
  #pragma unroll
  for (int mt=0; mt<2; mt++){
    const int rb = rows0 + mt*16;
    f32x4 acc[4];
    #pragma unroll
    for (int nt=0;nt<4;nt++) acc[nt] = fz;
    #pragma unroll
    for (int kt=0; kt<8; kt++){
      short8 a = *(const short8*)&ys[(size_t)(rb + l15)*256 + kt*32 + lhi*8];
      #pragma unroll
      for (int nt=0; nt<4; nt++){
        short8 bb = *(const short8*)&Wo[(size_t)(nt*16 + l15)*256 + kt*32 + lhi*8];
        acc[nt] = __builtin_amdgcn_mfma_f32_16x16x32_bf16(a, bb, acc[nt], 0, 0, 0);
      }
    }
    #pragma unroll
    for (int nt=0;nt<4;nt++){
      const int col = nt*16 + l15;
      const float bo = (col < 51) ? bout[col] : 0.f;
      #pragma unroll
      for (int r=0;r<4;r++){
        float v = (col < 51) ? (acc[nt][r] + bo) : -1e30f;
        lg[w][mt*16 + lhi*4 + r][col] = v;
      }
    }
  }
  __syncthreads();
  float xl = 0.f, ct = 0.f;
  if (lane < 32){
    const int grow = rows0 + lane;
    const float* Lr = &lg[w][lane][0];
    float m = Lr[0]; int am = 0;
    for (int i=1;i<51;i++){ float v = Lr[i]; if (v > m){ m = v; am = i; } }
    float s = 0.f;
    for (int i=0;i<51;i++) s += __expf(Lr[i] - m);
    const int bb = grow / 127;
    const int tt = grow - bb*127;
    const int tgt = x[bb*128 + tt + 1];
    const float nll = (m + __logf(s)) - Lr[tgt];
    const float mk = (tgt != 0) ? 1.f : 0.f;
    dout[PRED_OFF + grow] = (float)am;
    xl = nll * mk; ct = mk;
  }
  #pragma unroll
  for (int off=32; off>0; off>>=1){
    xl += __shfl_xor(xl, off);
    ct += __shfl_xor(ct, off);
  }
  if (lane == 0){
    atomicAdd(&dout[XLOSS_OFF], xl);
    atomicAdd(&dout[NPAD_OFF], ct);
  }
}

extern "C" void kernel_launch(void* const* d_in, const int* in_sizes, int n_in,
                              void* d_out, int out_size, void* d_ws, size_t ws_size,
                              hipStream_t stream){
  (void)in_sizes; (void)n_in; (void)out_size; (void)ws_size;
  const int*   x      = (const int*)  d_in[0];
  const float* emb_e  = (const float*)d_in[1];
  const float* emb_d  = (const float*)d_in[2];
  const float* Wih_f  = (const float*)d_in[3];
  const float* Whh_f  = (const float*)d_in[4];
  const float* bih_f  = (const float*)d_in[5];
  const float* bhh_f  = (const float*)d_in[6];
  const float* Wih_b  = (const float*)d_in[7];
  const float* Whh_b  = (const float*)d_in[8];
  const float* bih_b  = (const float*)d_in[9];
  const float* bhh_b  = (const float*)d_in[10];
  const float* Wdown  = (const float*)d_in[11];
  const float* bdown  = (const float*)d_in[12];
  const float* cbook  = (const float*)d_in[13];
  const float* Wup    = (const float*)d_in[14];
  const float* bup    = (const float*)d_in[15];
  const float* Wih_d  = (const float*)d_in[16];
  const float* Whh_d  = (const float*)d_in[17];
  const float* bih_d  = (const float*)d_in[18];
  const float* bhh_d  = (const float*)d_in[19];
  const float* Wout   = (const float*)d_in[20];
  const float* bout   = (const float*)d_in[21];
  float* dout = (float*)d_out;

  char* ws = (char*)d_ws;
  size_t off = 0;
  auto nxt = [&](size_t bytes)->char*{
    char* r = ws + off;
    off += (bytes + 255) & ~(size_t)255;
    return r;
  };
  signed char* Wq_f = (signed char*)nxt((size_t)196608);
  signed char* Wq_b = (signed char*)nxt((size_t)196608);
  signed char* Wq_d = (signed char*)nxt((size_t)196608);
  float* invF = (float*)nxt((size_t)768*4);
  float* invB = (float*)nxt((size_t)768*4);
  float* invD = (float*)nxt((size_t)768*4);
  float* Gf    = (float*)nxt((size_t)39168*4);
  float* Gb    = (float*)nxt((size_t)39168*4);
  float* Gd    = (float*)nxt((size_t)39168*4);
  u16*   Wo_bf = (u16*) nxt((size_t)16384*2);
  float* outH  = (float*)nxt((size_t)524288*4);
  float* hid   = (float*)nxt((size_t)262144*4);
  float* zcw   = (float*)nxt((size_t)786432*4);
  u16*   ysb   = (u16*)  nxt((size_t)33292288*2);

  hipLaunchKernelGGL(k_prep_wo, dim3(64), dim3(256), 0, stream, Wout, Wo_bf, dout);
  hipLaunchKernelGGL(k_prep_q, dim3(2304), dim3(64), 0, stream,
                     Whh_f, Whh_b, Whh_d, Wq_f, Wq_b, Wq_d, invF, invB, invD);
  hipLaunchKernelGGL(k_prep_g, dim3(459), dim3(256), 0, stream,
                     emb_e, emb_d, Wih_f, bih_f, bhh_f, Wih_b, bih_b, bhh_b, Wih_d,
                     Gf, Gb, Gd);
  hipLaunchKernelGGL((k_gru<0>), dim3(128), dim3(512), 0, stream,
                     Wq_f, Wq_b, invF, invB, Gf, Gb, bhh_f, bhh_b, x,
                     (const float*)nullptr, (const float*)nullptr, outH, (u16*)nullptr);
  hipLaunchKernelGGL(k_vq, dim3(1024), dim3(64), 0, stream,
                     outH, Wdown, bdown, cbook, Wup, bup, Wih_d, bih_d, bhh_d,
                     hid, zcw, dout);
  hipLaunchKernelGGL((k_gru<1>), dim3(64), dim3(512), 0, stream,
                     Wq_d, (const signed char*)nullptr, invD, (const float*)nullptr,
                     Gd, (const float*)nullptr, bhh_d, (const float*)nullptr, x,
                     zcw, hid, (float*)nullptr, ysb);
  hipLaunchKernelGGL(k_out, dim3(1016), dim3(256), 0, stream,
                     ysb, Wo_bf, bout, x, dout);
}

// Round 17
// 531.614 us; speedup vs baseline: 1.5363x; 1.1311x over previous
//
#include <hip/hip_runtime.h>
#include <cstdint>

typedef unsigned short u16;
typedef unsigned int u32;
typedef __attribute__((ext_vector_type(4))) int int4v;
typedef __attribute__((ext_vector_type(8))) short short8;
typedef __attribute__((ext_vector_type(4))) float f32x4;

// d_out layout (floats): [xloss(1), nonpadded(1), pred(130048), Q(1), idx(1024)]
#define XLOSS_OFF 0
#define NPAD_OFF  1
#define PRED_OFF  2
#define Q_OFF     130050
#define IDX_OFF   130051

__device__ __forceinline__ u16 f2b(float f){
  union { float f; unsigned int i; } c; c.f = f;
  unsigned int i = c.i;
  unsigned int r = (i + 0x7FFFu + ((i >> 16) & 1u)) >> 16;
  return (u16)r;
}

#define LOG2E 1.442695040889634f
__device__ __forceinline__ float fast_sigmoid(float x){
  return __builtin_amdgcn_rcpf(1.f + __builtin_amdgcn_exp2f(-LOG2E*x));
}
__device__ __forceinline__ float fast_tanh(float x){
  return 1.f - 2.f*__builtin_amdgcn_rcpf(1.f + __builtin_amdgcn_exp2f((2.f*LOG2E)*x));
}

// ---------------- prep: Wout bf16 copy + zero scalar outputs ----------------
__global__ __launch_bounds__(256) void k_prep_wo(
    const float* __restrict__ Wo, u16* __restrict__ oWo, float* __restrict__ dout){
  int idx = blockIdx.x*256 + threadIdx.x;      // 16384 threads
  if (idx == 0){ dout[XLOSS_OFF]=0.f; dout[NPAD_OFF]=0.f; dout[Q_OFF]=0.f; }
  int row = idx >> 8, k = idx & 255;
  oWo[idx] = (row < 51) ? f2b(Wo[row*256 + k]) : (u16)0;
}

// ---------------- prep: per-row i8 quantization of Whh_{f,b,d} ----------------
__global__ __launch_bounds__(64) void k_prep_q(
    const float* __restrict__ Wf, const float* __restrict__ Wb, const float* __restrict__ Wd,
    signed char* __restrict__ qf, signed char* __restrict__ qb, signed char* __restrict__ qd,
    float* __restrict__ invf, float* __restrict__ invb, float* __restrict__ invd){
  const int row = blockIdx.x;                  // 0..2303
  const int mat = row / 768, r = row - mat*768;
  const float* W = (mat==0 ? Wf : (mat==1 ? Wb : Wd)) + (size_t)r*256;
  signed char* q = (mat==0 ? qf : (mat==1 ? qb : qd)) + (size_t)r*256;
  float* inv     = (mat==0 ? invf : (mat==1 ? invb : invd));
  const int lane = threadIdx.x;
  float4 v = *(const float4*)(W + lane*4);
  float m = fmaxf(fmaxf(fabsf(v.x),fabsf(v.y)), fmaxf(fabsf(v.z),fabsf(v.w)));
  #pragma unroll
  for (int off=32; off>0; off>>=1) m = fmaxf(m, __shfl_xor(m, off));
  m = fmaxf(m, 1e-20f);
  const float s = 127.f / m;
  int a0 = __float2int_rn(v.x*s), a1 = __float2int_rn(v.y*s);
  int a2 = __float2int_rn(v.z*s), a3 = __float2int_rn(v.w*s);
  u32 packed = (a0&255) | ((a1&255)<<8) | ((a2&255)<<16) | ((a3&255)<<24);
  *(u32*)(q + lane*4) = packed;
  if (lane == 0) inv[r] = m * (1.f/127.f);
}

// ---------------- prep: gi lookup tables G[v][768] (f32) ----------------
__global__ __launch_bounds__(256) void k_prep_g(
    const float* __restrict__ emb_e, const float* __restrict__ emb_d,
    const float* __restrict__ Wih_f, const float* __restrict__ bih_f, const float* __restrict__ bhh_f,
    const float* __restrict__ Wih_b, const float* __restrict__ bih_b, const float* __restrict__ bhh_b,
    const float* __restrict__ Wih_d,
    float* __restrict__ Gf, float* __restrict__ Gb, float* __restrict__ Gd){
  int idx = blockIdx.x*256 + threadIdx.x;   // exactly 3*51*768 threads
  int tab = idx / 39168;
  int rem = idx - tab*39168;
  int v = rem / 768;
  int n = rem - v*768;
  float acc = 0.f;
  if (tab == 0){
    const float* e = emb_e + v*64; const float* w = Wih_f + n*64;
    for (int k=0;k<64;k++) acc += e[k]*w[k];
    acc += bih_f[n] + (n < 512 ? bhh_f[n] : 0.f);
    Gf[rem] = acc;
  } else if (tab == 1){
    const float* e = emb_e + v*64; const float* w = Wih_b + n*64;
    for (int k=0;k<64;k++) acc += e[k]*w[k];
    acc += bih_b[n] + (n < 512 ? bhh_b[n] : 0.f);
    Gb[rem] = acc;
  } else {
    const float* e = emb_d + v*64; const float* w = Wih_d + n*96 + 32;
    for (int k=0;k<64;k++) acc += e[k]*w[k];
    Gd[rem] = acc;
  }
}

// ---------------- GRU scan: 8 rows/block, gate work redistributed via LDS ----------
// 512 threads (8 waves, waves_per_eu(2,2)), 8 batch rows/block. MFMA layout as
// R15 (wave owns 32 h-cols x 3 gates, 96 resident weight VGPRs); only output
// rows 0-7 valid (hbf rows 8-15 zeroed). MFMA accs are dumped RAW (i32) to a
// gh LDS buffer; gate phase redistributed: wave w owns row w, lane owns 4
// CONSECUTIVE cols -> per-lane gate work halves and all gate-phase memory ops
// vectorize (G 3x dwordx4 issued at loop top, gh 3x ds_read_b128, zc LDS, ys
// 8B stores). R16 BUG FIX: dequant scale vectors must include the h-quant
// factor invHS (1/127 enc, 1/63 dec) — R16 used raw invS (127x too large ->
// saturated gates, 15% xloss error).
template<int MODE>
__global__ __launch_bounds__(512)
__attribute__((amdgpu_waves_per_eu(2, 2)))
void k_gru(
    const signed char* __restrict__ W0, const signed char* __restrict__ W1,
    const float* __restrict__ I0, const float* __restrict__ I1,
    const float* __restrict__ G0, const float* __restrict__ G1,
    const float* __restrict__ bhh0, const float* __restrict__ bhh1,
    const int* __restrict__ x,
    const float* __restrict__ zc, const float* __restrict__ h0g,
    float* __restrict__ out_h, u16* __restrict__ ys){
  __shared__ signed char hbf[2*4096];               // [2][16 rows][256], swizzled; rows 8-15 zero
  __shared__ int xsh[1024];                         // [8][128] tokens
  __shared__ int gh[8*772];                         // [8 rows][768+4] raw i32 accs
  __shared__ float zcs[(MODE==1) ? 8*768 : 4];      // decoder per-row constants

  const int tid = threadIdx.x;
  const int lane = tid & 63;
  const int wave = tid >> 6;                 // 0..7
  const int l15 = lane & 15, lhi = lane >> 4;

  bool fwd = true; int gb;
  const signed char* W; const float* G; const float* bhh; const float* invS;
  if (MODE == 0){
    int bi = blockIdx.x;
    fwd = bi < 128; gb = fwd ? bi : bi - 128;
    W = fwd ? W0 : W1; G = fwd ? G0 : G1; bhh = fwd ? bhh0 : bhh1;
    invS = fwd ? I0 : I1;
  } else {
    gb = blockIdx.x; W = W0; G = G0; bhh = bhh0; invS = I0;
  }
  const int b0 = gb * 8;
  const int nT = (MODE == 0) ? 128 : 127;
  const float HS    = (MODE == 0) ? 127.f : 63.f;
  const float invHS = (MODE == 0) ? (1.f/127.f) : (1.f/63.f);

  // ---- persistent weights: [gate*2+half][kt], 24 x int4v = 96 VGPRs, pinned ----
  int4v wq[6][4];
  #pragma unroll
  for (int g=0; g<3; g++){
    #pragma unroll
    for (int hh=0; hh<2; hh++){
      const signed char* p = W + (size_t)(g*256 + wave*32 + hh*16 + l15)*256 + lhi*16;
      #pragma unroll
      for (int kt=0; kt<4; kt++)
        wq[g*2+hh][kt] = *(const int4v*)(p + kt*64);
    }
  }
  #pragma unroll
  for (int kt=0; kt<4; kt++){
    asm volatile("" : "+v"(wq[0][kt]));
    asm volatile("" : "+v"(wq[1][kt]));
    asm volatile("" : "+v"(wq[2][kt]));
    asm volatile("" : "+v"(wq[3][kt]));
    asm volatile("" : "+v"(wq[4][kt]));
    asm volatile("" : "+v"(wq[5][kt]));
  }

  // ---- gate-phase identity: wave = row, lane -> 4 consecutive cols ----
  const int gm = wave;                       // row 0..7
  const int c4 = lane * 4;                   // cols c4..c4+3
  f32x4 isr4 = *(const f32x4*)(invS + c4);
  f32x4 isz4 = *(const f32x4*)(invS + 256 + c4);
  f32x4 isn4 = *(const f32x4*)(invS + 512 + c4);
  #pragma unroll
  for (int i=0;i<4;i++){ isr4[i] *= invHS; isz4[i] *= invHS; isn4[i] *= invHS; }
  const f32x4 bn4 = *(const f32x4*)(bhh + 512 + c4);

  // stage tokens; zero hbf (rows 8-15 stay zero forever); stage decoder zc
  for (int i = tid; i < 1024; i += 512) xsh[i] = x[b0*128 + i];
  for (int i = tid*4; i < 8192; i += 2048) *(int*)&hbf[i] = 0;
  if (MODE == 1){
    const f32x4* src = (const f32x4*)(zc + (size_t)b0*768);
    f32x4* dst = (f32x4*)zcs;
    for (int i = tid; i < 1536; i += 512) dst[i] = src[i];
  }
  __syncthreads();

  // init h state (f32 regs) + decoder h0 into buf0
  float hreg[4];
  #pragma unroll
  for (int i=0;i<4;i++) hreg[i] = 0.f;
  if (MODE == 1){
    f32x4 h0v = *(const f32x4*)(h0g + (size_t)(b0+gm)*256 + c4);
    u32 pk = 0;
    #pragma unroll
    for (int i=0;i<4;i++){
      hreg[i] = h0v[i];
      int q = __float2int_rn(fminf(fmaxf(h0v[i]*HS, -127.f), 127.f));
      pk |= (u32)(q & 255) << (8*i);
    }
    *(u32*)&hbf[gm*256 + (c4 ^ (gm<<4))] = pk;
  }
  __syncthreads();

  // A-fragment byte offsets (row l15, K-slice kt*64 + lhi*16, XOR-swizzled)
  int aoff[4];
  #pragma unroll
  for (int kt=0; kt<4; kt++)
    aoff[kt] = l15*256 + ((kt*64 + lhi*16) ^ (l15<<4));

  int cur = 0;
  for (int t=0; t<nT; ++t){
    // G loads issued FIRST: latency drains under the MFMA phase.
    const int te = (MODE==0 && !fwd) ? (127 - t) : t;
    const int tok = xsh[(gm<<7) + te];
    const float* Gp = G + (size_t)tok*768 + c4;
    f32x4 gr4 = *(const f32x4*)(Gp);
    f32x4 gz4 = *(const f32x4*)(Gp + 256);
    f32x4 gn4 = *(const f32x4*)(Gp + 512);

    const signed char* hb = hbf + (cur<<12);
    int4v af[4];
    #pragma unroll
    for (int kt=0; kt<4; kt++) af[kt] = *(const int4v*)(hb + aoff[kt]);

    int4v acc[6];
    #pragma unroll
    for (int j=0;j<6;j++) acc[j] = (int4v){0,0,0,0};
    #pragma unroll
    for (int kt=0; kt<4; kt++)
      #pragma unroll
      for (int j=0;j<6;j++)
        acc[j] = __builtin_amdgcn_mfma_i32_16x16x64_i8(af[kt], wq[j][kt], acc[j], 0,0,0);

    // dump raw accs to gh (valid rows 0..7 live in lanes lhi<2)
    if (lhi < 2){
      #pragma unroll
      for (int j=0;j<6;j++){
        const int g = j >> 1;
        const int col = wave*32 + (j&1)*16 + l15;
        #pragma unroll
        for (int r=0;r<4;r++)
          gh[(4*lhi+r)*772 + g*256 + col] = acc[j][r];
      }
    }
    __syncthreads();

    // ---- gate phase: wave gm handles row gm, lane 4 consecutive cols ----
    int4v hiR = *(const int4v*)&gh[gm*772 + c4];
    int4v hiZ = *(const int4v*)&gh[gm*772 + 256 + c4];
    int4v hiN = *(const int4v*)&gh[gm*772 + 512 + c4];
    f32x4 zr4 = {0.f,0.f,0.f,0.f}, zz4 = zr4, zn4 = zr4;
    if (MODE == 1){
      zr4 = *(const f32x4*)&zcs[gm*768 + c4];
      zz4 = *(const f32x4*)&zcs[gm*768 + 256 + c4];
      zn4 = *(const f32x4*)&zcs[gm*768 + 512 + c4];
    }
    u32 pk = 0;
    #pragma unroll
    for (int i=0;i<4;i++){
      float gr = gr4[i] + zr4[i];
      float gz = gz4[i] + zz4[i];
      float gn = gn4[i] + zn4[i];
      float rg = fast_sigmoid((float)hiR[i]*isr4[i] + gr);
      float zg = fast_sigmoid((float)hiZ[i]*isz4[i] + gz);
      float nn = fast_tanh(gn + rg*((float)hiN[i]*isn4[i] + bn4[i]));
      float hv = nn + zg*(hreg[i] - nn);
      hreg[i] = hv;
      int q = __float2int_rn(fminf(fmaxf(hv*HS, -127.f), 127.f));
      pk |= (u32)(q & 255) << (8*i);
    }
    *(u32*)&hbf[((cur^1)<<12) + gm*256 + (c4 ^ (gm<<4))] = pk;
    if (MODE == 1){
      u32 lo = (u32)f2b(hreg[0]) | ((u32)f2b(hreg[1]) << 16);
      u32 hi = (u32)f2b(hreg[2]) | ((u32)f2b(hreg[3]) << 16);
      uint2 v; v.x = lo; v.y = hi;
      *(uint2*)&ys[((size_t)(b0+gm)*127 + t)*256 + c4] = v;
    }
    __syncthreads();
    cur ^= 1;
  }

  if (MODE == 0){
    f32x4 o = {hreg[0], hreg[1], hreg[2], hreg[3]};
    *(f32x4*)(out_h + (size_t)(b0+gm)*512 + (fwd ? 0 : 256) + c4) = o;
  }
}

// ---------------- VQ: z, argmin codebook, Q, idx, decoder h0, zc ----------------
__global__ __launch_bounds__(64) void k_vq(
    const float* __restrict__ outH, const float* __restrict__ Wdown, const float* __restrict__ bdown,
    const float* __restrict__ cb, const float* __restrict__ Wup, const float* __restrict__ bup,
    const float* __restrict__ Wihd, const float* __restrict__ bihd, const float* __restrict__ bhhd,
    float* __restrict__ hidden, float* __restrict__ zc, float* __restrict__ dout){
  const int b = blockIdx.x;
  const int lane = threadIdx.x;
  __shared__ float oh[512];
  __shared__ float zsh[32];
  __shared__ float qsh[32];
  {
    const float* src = outH + (size_t)b*512 + lane*8;
    *(float4*)&oh[lane*8]   = *(const float4*)src;
    *(float4*)&oh[lane*8+4] = *(const float4*)(src+4);
  }
  __syncthreads();
  if (lane < 32){
    float acc = bdown[lane];
    const float* wr = Wdown + lane*512;
    for (int k=0;k<512;k++) acc += wr[k]*oh[k];
    zsh[lane] = acc;
  }
  __syncthreads();
  float bd = 3.4e38f; int bi = 0;
  for (int c8=0;c8<8;c8++){
    const int c = lane*8 + c8;
    const float* cr = cb + c*32;
    float d = 0.f;
    #pragma unroll
    for (int k=0;k<32;k++){ float df = zsh[k]-cr[k]; d += df*df; }
    if (d < bd){ bd = d; bi = c; }
  }
  #pragma unroll
  for (int offm=32; offm>0; offm>>=1){
    float od = __shfl_xor(bd, offm);
    int   oi = __shfl_xor(bi, offm);
    if (od < bd || (od == bd && oi < bi)){ bd = od; bi = oi; }
  }
  if (lane == 0){
    atomicAdd(&dout[Q_OFF], bd * (0.2f/32.f));
    dout[IDX_OFF + b] = (float)bi;
  }
  if (lane < 32) qsh[lane] = cb[(size_t)bi*32 + lane];
  __syncthreads();
  #pragma unroll
  for (int i=0;i<4;i++){
    const int o = lane*4 + i;
    float acc = bup[o];
    const float* wr = Wup + o*32;
    #pragma unroll
    for (int k=0;k<32;k++) acc += wr[k]*qsh[k];
    hidden[(size_t)b*256 + o] = acc;
  }
  #pragma unroll
  for (int i=0;i<12;i++){
    const int o = lane*12 + i;
    float acc = bihd[o] + (o < 512 ? bhhd[o] : 0.f);
    const float* wr = Wihd + (size_t)o*96;
    #pragma unroll
    for (int k=0;k<32;k++) acc += wr[k]*qsh[k];
    zc[(size_t)b*768 + o] = acc;
  }
}

// ---------------- output: logits, log-softmax, nll, argmax ----------------
__global__ __launch_bounds__(256) void k_out(
    const u16* __restrict__ ys, const u16* __restrict__ Wo,
    const float* __restrict__ bout, const int* __restrict__ x,
    float* __restrict__ dout){
  const int tid = threadIdx.x;
  const int w = tid >> 6, lane = tid & 63;
  const int l15 = lane & 15, lhi = lane >> 4;
  __shared__ float lg[4][32][66];
  const int rows0 = blockIdx.x*128 + w*32;
  const f32x4 fz = {0.f,0.f,0.f,0.f};
  #pragma unroll
  for (int mt=0; mt<2; mt++){
    const int rb = rows0 + mt*16;
    f32x4 acc[4];
    #pragma unroll
    for (int nt=0;nt<4;nt++) acc[nt] = fz;
    #pragma unroll
    for (int kt=0; kt<8; kt++){
      short8 a = *(const short8*)&ys[(size_t)(rb + l15)*256 + kt*32 + lhi*8];
      #pragma unroll
      for (int nt=0; nt<4; nt++){
        short8 bb = *(const short8*)&Wo[(size_t)(nt*16 + l15)*256 + kt*32 + lhi*8];
        acc[nt] = __builtin_amdgcn_mfma_f32_16x16x32_bf16(a, bb, acc[nt], 0, 0, 0);
      }
    }
    #pragma unroll
    for (int nt=0;nt<4;nt++){
      const int col = nt*16 + l15;
      const float bo = (col < 51) ? bout[col] : 0.f;
      #pragma unroll
      for (int r=0;r<4;r++){
        float v = (col < 51) ? (acc[nt][r] + bo) : -1e30f;
        lg[w][mt*16 + lhi*4 + r][col] = v;
      }
    }
  }
  __syncthreads();
  float xl = 0.f, ct = 0.f;
  if (lane < 32){
    const int grow = rows0 + lane;
    const float* Lr = &lg[w][lane][0];
    float m = Lr[0]; int am = 0;
    for (int i=1;i<51;i++){ float v = Lr[i]; if (v > m){ m = v; am = i; } }
    float s = 0.f;
    for (int i=0;i<51;i++) s += __expf(Lr[i] - m);
    const int bb = grow / 127;
    const int tt = grow - bb*127;
    const int tgt = x[bb*128 + tt + 1];
    const float nll = (m + __logf(s)) - Lr[tgt];
    const float mk = (tgt != 0) ? 1.f : 0.f;
    dout[PRED_OFF + grow] = (float)am;
    xl = nll * mk; ct = mk;
  }
  #pragma unroll
  for (int off=32; off>0; off>>=1){
    xl += __shfl_xor(xl, off);
    ct += __shfl_xor(ct, off);
  }
  if (lane == 0){
    atomicAdd(&dout[XLOSS_OFF], xl);
    atomicAdd(&dout[NPAD_OFF], ct);
  }
}

extern "C" void kernel_launch(void* const* d_in, const int* in_sizes, int n_in,
                              void* d_out, int out_size, void* d_ws, size_t ws_size,
                              hipStream_t stream){
  (void)in_sizes; (void)n_in; (void)out_size; (void)ws_size;
  const int*   x      = (const int*)  d_in[0];
  const float* emb_e  = (const float*)d_in[1];
  const float* emb_d  = (const float*)d_in[2];
  const float* Wih_f  = (const float*)d_in[3];
  const float* Whh_f  = (const float*)d_in[4];
  const float* bih_f  = (const float*)d_in[5];
  const float* bhh_f  = (const float*)d_in[6];
  const float* Wih_b  = (const float*)d_in[7];
  const float* Whh_b  = (const float*)d_in[8];
  const float* bih_b  = (const float*)d_in[9];
  const float* bhh_b  = (const float*)d_in[10];
  const float* Wdown  = (const float*)d_in[11];
  const float* bdown  = (const float*)d_in[12];
  const float* cbook  = (const float*)d_in[13];
  const float* Wup    = (const float*)d_in[14];
  const float* bup    = (const float*)d_in[15];
  const float* Wih_d  = (const float*)d_in[16];
  const float* Whh_d  = (const float*)d_in[17];
  const float* bih_d  = (const float*)d_in[18];
  const float* bhh_d  = (const float*)d_in[19];
  const float* Wout   = (const float*)d_in[20];
  const float* bout   = (const float*)d_in[21];
  float* dout = (float*)d_out;

  char* ws = (char*)d_ws;
  size_t off = 0;
  auto nxt = [&](size_t bytes)->char*{
    char* r = ws + off;
    off += (bytes + 255) & ~(size_t)255;
    return r;
  };
  signed char* Wq_f = (signed char*)nxt((size_t)196608);
  signed char* Wq_b = (signed char*)nxt((size_t)196608);
  signed char* Wq_d = (signed char*)nxt((size_t)196608);
  float* invF = (float*)nxt((size_t)768*4);
  float* invB = (float*)nxt((size_t)768*4);
  float* invD = (float*)nxt((size_t)768*4);
  float* Gf    = (float*)nxt((size_t)39168*4);
  float* Gb    = (float*)nxt((size_t)39168*4);
  float* Gd    = (float*)nxt((size_t)39168*4);
  u16*   Wo_bf = (u16*) nxt((size_t)16384*2);
  float* outH  = (float*)nxt((size_t)524288*4);
  float* hid   = (float*)nxt((size_t)262144*4);
  float* zcw   = (float*)nxt((size_t)786432*4);
  u16*   ysb   = (u16*)  nxt((size_t)33292288*2);

  hipLaunchKernelGGL(k_prep_wo, dim3(64), dim3(256), 0, stream, Wout, Wo_bf, dout);
  hipLaunchKernelGGL(k_prep_q, dim3(2304), dim3(64), 0, stream,
                     Whh_f, Whh_b, Whh_d, Wq_f, Wq_b, Wq_d, invF, invB, invD);
  hipLaunchKernelGGL(k_prep_g, dim3(459), dim3(256), 0, stream,
                     emb_e, emb_d, Wih_f, bih_f, bhh_f, Wih_b, bih_b, bhh_b, Wih_d,
                     Gf, Gb, Gd);
  hipLaunchKernelGGL((k_gru<0>), dim3(256), dim3(512), 0, stream,
                     Wq_f, Wq_b, invF, invB, Gf, Gb, bhh_f, bhh_b, x,
                     (const float*)nullptr, (const float*)nullptr, outH, (u16*)nullptr);
  hipLaunchKernelGGL(k_vq, dim3(1024), dim3(64), 0, stream,
                     outH, Wdown, bdown, cbook, Wup, bup, Wih_d, bih_d, bhh_d,
                     hid, zcw, dout);
  hipLaunchKernelGGL((k_gru<1>), dim3(128), dim3(512), 0, stream,
                     Wq_d, (const signed char*)nullptr, invD, (const float*)nullptr,
                     Gd, (const float*)nullptr, bhh_d, (const float*)nullptr, x,
                     zcw, hid, (float*)nullptr, ysb);
  hipLaunchKernelGGL(k_out, dim3(1016), dim3(256), 0, stream,
                     ysb, Wo_bf, bout, x, dout);
}